// Round 10
// baseline (280.855 us; speedup 1.0000x reference)
//
#include <hip/hip_runtime.h>
#include <hip/hip_bf16.h>

typedef __bf16 bf16x8 __attribute__((ext_vector_type(8)));
typedef float f32x4 __attribute__((ext_vector_type(4)));
typedef float f32x16 __attribute__((ext_vector_type(16)));
typedef unsigned u32x2 __attribute__((ext_vector_type(2)));

#define MFMA16(a, b, c) __builtin_amdgcn_mfma_f32_16x16x32_bf16(a, b, c, 0, 0, 0)
#define MFMA32(a, b, c) __builtin_amdgcn_mfma_f32_32x32x16_bf16(a, b, c, 0, 0, 0)

#if defined(__has_builtin)
#if __has_builtin(__builtin_amdgcn_permlane32_swap)
#define HAVE_PL32 1
#endif
#endif

static constexpr int NSP = 4096;   // H*W
static constexpr float SCALE_L2E = 0.25f * 1.4426950408889634f;  // SCALE * log2(e)

__device__ __forceinline__ bf16x8 ld_frag(const void* p) {
  int4 v = *(const int4*)p;
  return __builtin_bit_cast(bf16x8, v);
}

__device__ __forceinline__ unsigned pk2(float a, float b) {
  unsigned short x = __builtin_bit_cast(unsigned short, (__bf16)a);
  unsigned short y = __builtin_bit_cast(unsigned short, (__bf16)b);
  return (unsigned)x | ((unsigned)y << 16);
}

__device__ __forceinline__ void load_lds16(const void* g, void* l) {
  __builtin_amdgcn_global_load_lds(
      (const __attribute__((address_space(1))) unsigned*)g,
      (__attribute__((address_space(3))) unsigned*)l, 16, 0, 0);
}

// ---------------- K0: weight prep ------------------------------------------
__global__ void k_prep(const float* __restrict__ Wq, const float* __restrict__ bq,
                       const float* __restrict__ Wk, const float* __restrict__ Wv,
                       const float* __restrict__ Wo,
                       __bf16* __restrict__ wqb, __bf16* __restrict__ wkb,
                       __bf16* __restrict__ wvb, __bf16* __restrict__ wob,
                       float* __restrict__ bqs) {
  int i = blockIdx.x * 256 + threadIdx.x;
  if (i < 16384)      wqb[i]          = (__bf16)(Wq[i] * SCALE_L2E);
  else if (i < 49152) wkb[i - 16384]  = (__bf16)Wk[i - 16384];
  else if (i < 81920) wvb[i - 49152]  = (__bf16)Wv[i - 49152];
  else if (i < 98304) wob[i - 81920]  = (__bf16)Wo[i - 81920];
  if (i < 128) bqs[i] = bq[i] * SCALE_L2E;
}

// Per-wave transposed tile store (4-bit XOR swizzle) ------------------------
template <bool SWZ>
__device__ __forceinline__ void store_tile_T(char* myt, const f32x4* acc, int g, int r,
                                             __bf16* dst_base) {
#pragma unroll
  for (int oc = 0; oc < 8; ++oc) {
#pragma unroll
    for (int rr = 0; rr < 4; ++rr) {
      int o = oc * 16 + g * 4 + rr;
      int byte = (r << 8) + (((o << 1)) ^ (r << 4));
      *(__bf16*)(myt + byte) = (__bf16)acc[oc][rr];
    }
  }
  int l = g * 16 + r;
#pragma unroll
  for (int p = 0; p < 4; ++p) {
    int u = p * 64 + l, row = u >> 4, seg = u & 15;
    int byte = (row << 8) + (seg << 4);
    if (!SWZ) byte ^= (row & 15) << 4;
    int4 v = *(int4*)(myt + byte);
    *(int4*)(dst_base + row * 128 + seg * 8) = v;
  }
}

// ---------------- K1: fused Q / K+V projections ----------------------------
__global__ __launch_bounds__(256) void k_proj(const float* __restrict__ xq,
                                              const float* __restrict__ xkv,
                                              const __bf16* __restrict__ wqb,
                                              const __bf16* __restrict__ wkb,
                                              const __bf16* __restrict__ wvb,
                                              const float* __restrict__ bqs,
                                              const float* __restrict__ bk,
                                              const float* __restrict__ bv,
                                              __bf16* __restrict__ Qt,
                                              __bf16* __restrict__ Kt,
                                              __bf16* __restrict__ Vm) {
  const int t = threadIdx.x, w = t >> 6, l = t & 63, r = l & 15, g = l >> 4;
  __shared__ __align__(16) char lds[16384];
  char* myt = lds + (w << 12);

  if (blockIdx.x < 256) {
    const int b = blockIdx.x >> 6;
    const int n0 = (blockIdx.x & 63) << 6;
    const int nl = n0 + (w << 4) + r;
    const float* xb = xq + ((size_t)b << 19);
    bf16x8 bx[4];
#pragma unroll
    for (int cc = 0; cc < 4; ++cc) {
#pragma unroll
      for (int i = 0; i < 8; ++i) {
        int c = cc * 32 + g * 8 + i;
        bx[cc][i] = (__bf16)xb[c * 4096 + nl];
      }
    }
    f32x4 acc[8];
#pragma unroll
    for (int oc = 0; oc < 8; ++oc)
#pragma unroll
      for (int rr = 0; rr < 4; ++rr) acc[oc][rr] = bqs[oc * 16 + g * 4 + rr];
#pragma unroll
    for (int oc = 0; oc < 8; ++oc) {
#pragma unroll
      for (int cc = 0; cc < 4; ++cc) {
        bf16x8 a = ld_frag(wqb + (oc * 16 + r) * 128 + cc * 32 + g * 8);
        acc[oc] = MFMA16(a, bx[cc], acc[oc]);
      }
    }
    store_tile_T<false>(myt, acc, g, r, Qt + ((size_t)(b * NSP + n0 + w * 16)) * 128);
  } else {
    const int bid = blockIdx.x - 256;
    const int b = bid >> 6;
    const int n0 = (bid & 63) << 6;
    const int nl = n0 + (w << 4) + r;
    const float* xb = xkv + ((size_t)b << 20);
    bf16x8 bx[8];
#pragma unroll
    for (int cc = 0; cc < 8; ++cc) {
#pragma unroll
      for (int i = 0; i < 8; ++i) {
        int c = cc * 32 + g * 8 + i;
        bx[cc][i] = (__bf16)xb[(size_t)c * 4096 + nl];
      }
    }
    f32x4 acc[8];
#pragma unroll
    for (int oc = 0; oc < 8; ++oc)
#pragma unroll
      for (int rr = 0; rr < 4; ++rr) acc[oc][rr] = bk[oc * 16 + g * 4 + rr];
#pragma unroll
    for (int oc = 0; oc < 8; ++oc) {
#pragma unroll
      for (int cc = 0; cc < 8; ++cc) {
        bf16x8 a = ld_frag(wkb + (oc * 16 + r) * 256 + cc * 32 + g * 8);
        acc[oc] = MFMA16(a, bx[cc], acc[oc]);
      }
    }
    store_tile_T<true>(myt, acc, g, r, Kt + ((size_t)(b * NSP + n0 + w * 16)) * 128);

    f32x4 av[8];
#pragma unroll
    for (int oc = 0; oc < 8; ++oc)
#pragma unroll
      for (int rr = 0; rr < 4; ++rr) av[oc][rr] = bv[oc * 16 + g * 4 + rr];
#pragma unroll
    for (int oc = 0; oc < 8; ++oc) {
#pragma unroll
      for (int cc = 0; cc < 8; ++cc) {
        bf16x8 a = ld_frag(wvb + (oc * 16 + r) * 256 + cc * 32 + g * 8);
        av[oc] = MFMA16(a, bx[cc], av[oc]);
      }
    }
    // V [B][128][N], granule-swizzled: key n at n ^ (((ch>>1)&3)<<3)
#pragma unroll
    for (int oc = 0; oc < 8; ++oc) {
#pragma unroll
      for (int rr = 0; rr < 4; ++rr) {
        int o = oc * 16 + g * 4 + rr;
        Vm[((size_t)(b * 128 + o) << 12) + (nl ^ (((o >> 1) & 3) << 3))] = (__bf16)av[oc][rr];
      }
    }
  }
}

// ======================= flash common prologue macro =======================
#define FLASH_IDS                                                              \
  const int bid = blockIdx.x;                                                  \
  const int combo = bid & (4 * SPLIT - 1), qtile = bid / (4 * SPLIT);          \
  const int b = combo & 3, ks = combo >> 2;                                    \
  const int q0 = qtile << 7;                                                   \
  const int NK = NSP / SPLIT;                                                  \
  const int t = threadIdx.x, w = t >> 6, l = t & 63;                           \
  const int q31 = l & 31, hi = l >> 5;                                         \
  const int swz = (q31 & 15) << 4;                                             \
  const int swzV = ((q31 >> 1) & 3) << 4;                                      \
  const int qA = q0 + w * 32 + q31;                                            \
  const __bf16* qp = Qt + ((size_t)(b * NSP + qA)) * 128;                      \
  bf16x8 qf[8];                                                                \
  _Pragma("unroll") for (int cc = 0; cc < 8; ++cc)                             \
      qf[cc] = ld_frag(qp + cc * 16 + hi * 8);                                 \
  f32x16 acc[4];                                                               \
  _Pragma("unroll") for (int c = 0; c < 4; ++c)                                \
      _Pragma("unroll") for (int i = 0; i < 16; ++i) acc[c][i] = 0.f;          \
  f32x4 lp = (f32x4){0.f, 0.f, 0.f, 0.f};                                      \
  const char* kbase = (const char*)(Kt + ((size_t)(b * NSP) + ks * NK) * 128); \
  const char* vbase = (const char*)(Vm + (size_t)b * 128 * NSP + ks * NK);

#define FLASH_EPILOGUE                                                         \
  float lsum = (lp[0] + lp[1]) + (lp[2] + lp[3]);                              \
  lsum += __shfl_xor(lsum, 32);                                                \
  const size_t rowA = (size_t)((ks * 4 + b) * NSP + qA) * 128;                 \
  _Pragma("unroll") for (int cht = 0; cht < 4; ++cht) {                        \
    _Pragma("unroll") for (int qq = 0; qq < 4; ++qq) {                         \
      uint2 va;                                                                \
      va.x = pk2(acc[cht][4 * qq + 0], acc[cht][4 * qq + 1]);                  \
      va.y = pk2(acc[cht][4 * qq + 2], acc[cht][4 * qq + 3]);                  \
      *(uint2*)(Op + rowA + cht * 32 + qq * 8 + hi * 4) = va;                  \
    }                                                                          \
  }                                                                            \
  if (hi == 0) Ml[(size_t)(ks * 4 + b) * NSP + qA] = make_float2(0.f, lsum);

// softmax + pack (shared): input s, produces pA[4][2]
#define FLASH_SOFTMAX_PACK                                                     \
  _Pragma("unroll") for (int i = 0; i < 16; ++i) s[i] = exp2f(s[i]);           \
  _Pragma("unroll") for (int i = 0; i < 16; ++i) lp[i & 3] += s[i];            \
  unsigned pA[4][2];                                                           \
  _Pragma("unroll") for (int q4 = 0; q4 < 4; ++q4) {                           \
    pA[q4][0] = pk2(s[4 * q4 + 0], s[4 * q4 + 1]);                             \
    pA[q4][1] = pk2(s[4 * q4 + 2], s[4 * q4 + 3]);                             \
  }

#define EXCHANGE_SHFL                                                          \
  unsigned rA[4][2];                                                           \
  _Pragma("unroll") for (int q4 = 0; q4 < 4; ++q4) {                           \
    rA[q4][0] = __shfl_xor(pA[q4][0], 32);                                     \
    rA[q4][1] = __shfl_xor(pA[q4][1], 32);                                     \
  }                                                                            \
  pfA4.x = hi ? rA[1][0] : pA[0][0];                                           \
  pfA4.y = hi ? rA[1][1] : pA[0][1];                                           \
  pfA4.z = hi ? pA[1][0] : rA[0][0];                                           \
  pfA4.w = hi ? pA[1][1] : rA[0][1];                                           \
  pfB4.x = hi ? rA[3][0] : pA[2][0];                                           \
  pfB4.y = hi ? rA[3][1] : pA[2][1];                                           \
  pfB4.z = hi ? pA[3][0] : rA[2][0];                                           \
  pfB4.w = hi ? pA[3][1] : rA[2][1];

#ifdef HAVE_PL32
#define EXCHANGE_PL32                                                          \
  {                                                                            \
    u32x2 r_;                                                                  \
    r_ = __builtin_amdgcn_permlane32_swap(pA[0][0], pA[1][0], false, false);   \
    pfA4.x = r_[0]; pfA4.z = r_[1];                                            \
    r_ = __builtin_amdgcn_permlane32_swap(pA[0][1], pA[1][1], false, false);   \
    pfA4.y = r_[0]; pfA4.w = r_[1];                                            \
    r_ = __builtin_amdgcn_permlane32_swap(pA[2][0], pA[3][0], false, false);   \
    pfB4.x = r_[0]; pfB4.z = r_[1];                                            \
    r_ = __builtin_amdgcn_permlane32_swap(pA[2][1], pA[3][1], false, false);   \
    pfB4.y = r_[0]; pfB4.w = r_[1];                                            \
  }
#else
#define EXCHANGE_PL32 EXCHANGE_SHFL
#endif

// ---------------- V0: R8 exact (anchor; runs LAST -> authoritative) --------
template <int SPLIT>
__global__ __launch_bounds__(256, 3) void k_flash0(const __bf16* __restrict__ Qt,
                                                   const __bf16* __restrict__ Kt,
                                                   const __bf16* __restrict__ Vm,
                                                   __bf16* __restrict__ Op,
                                                   float2* __restrict__ Ml) {
  FLASH_IDS
  __shared__ __align__(16) char kl[2][8192];
  __shared__ __align__(16) char vl[2][8192];
  auto STAGE = [&](int bi, int tt) {
#pragma unroll
    for (int i = 0; i < 2; ++i) {
      int u = i * 256 + t;
      load_lds16(kbase + tt * 8192 + u * 16, &kl[bi][u * 16]);
    }
#pragma unroll
    for (int i = 0; i < 2; ++i) {
      int u = i * 256 + t, ch = u >> 2, ko = u & 3;
      load_lds16(vbase + (size_t)ch * 8192 + tt * 64 + ko * 16, &vl[bi][u * 16]);
    }
  };
  STAGE(0, 0);
  const int nit = NK / 32;
  for (int it = 0; it < nit; ++it) {
    const int cur = it & 1;
    asm volatile("s_barrier" ::: "memory");
    if (it + 1 < nit) {
      STAGE(cur ^ 1, it + 1);
      asm volatile("s_waitcnt vmcnt(4)" ::: "memory");
    } else {
      asm volatile("s_waitcnt vmcnt(0)" ::: "memory");
    }
    __builtin_amdgcn_sched_barrier(0);
    asm volatile("s_barrier" ::: "memory");

    const char* kt = kl[cur];
    f32x16 sX = {}, sY = {};
    __builtin_amdgcn_s_setprio(1);
#pragma unroll
    for (int cc = 0; cc < 4; ++cc) {
      bf16x8 kf0 = ld_frag(kt + (q31 << 8) + ((cc * 32 + hi * 16) ^ swz));
      bf16x8 kf1 = ld_frag(kt + (q31 << 8) + (((cc + 4) * 32 + hi * 16) ^ swz));
      sX = MFMA32(kf0, qf[cc], sX);
      sY = MFMA32(kf1, qf[cc + 4], sY);
    }
    __builtin_amdgcn_s_setprio(0);
    f32x16 s;
#pragma unroll
    for (int i = 0; i < 16; ++i) s[i] = sX[i] + sY[i];

    FLASH_SOFTMAX_PACK
    uint4 pfA4, pfB4;
    EXCHANGE_SHFL

    const char* vt = vl[cur];
    bf16x8 pfA = __builtin_bit_cast(bf16x8, pfA4);
    bf16x8 pfB = __builtin_bit_cast(bf16x8, pfB4);
    __builtin_amdgcn_s_setprio(1);
#pragma unroll
    for (int cht = 0; cht < 4; ++cht) {
      bf16x8 vf0 = ld_frag(vt + (cht * 32 + q31) * 64 + ((hi * 16) ^ swzV));
      bf16x8 vf1 = ld_frag(vt + (cht * 32 + q31) * 64 + ((32 + hi * 16) ^ swzV));
      acc[cht] = MFMA32(vf0, pfA, acc[cht]);
      acc[cht] = MFMA32(vf1, pfB, acc[cht]);
    }
    __builtin_amdgcn_s_setprio(0);
  }
  FLASH_EPILOGUE
}

// ---------------- V2: V direct from global/L2 (no V staging) ---------------
template <int SPLIT>
__global__ __launch_bounds__(256, 2) void k_flash2(const __bf16* __restrict__ Qt,
                                                   const __bf16* __restrict__ Kt,
                                                   const __bf16* __restrict__ Vm,
                                                   __bf16* __restrict__ Op,
                                                   float2* __restrict__ Ml) {
  FLASH_IDS
  __shared__ __align__(16) char kl[2][8192];
  auto STAGE_K = [&](int bi, int tt) {
#pragma unroll
    for (int i = 0; i < 2; ++i) {
      int u = i * 256 + t;
      load_lds16(kbase + tt * 8192 + u * 16, &kl[bi][u * 16]);
    }
  };
  STAGE_K(0, 0);
  __syncthreads();
  const int nit = NK / 32;
  for (int it = 0; it < nit; ++it) {
    const int cur = it & 1;
    if (it + 1 < nit) STAGE_K(cur ^ 1, it + 1);
    // V fragments direct from global (L2-resident); issued early, consumed at PV
    int4 vr[8];
#pragma unroll
    for (int cht = 0; cht < 4; ++cht)
#pragma unroll
      for (int kb = 0; kb < 2; ++kb)
        vr[cht * 2 + kb] = *(const int4*)(vbase + (size_t)(cht * 32 + q31) * 8192 +
                                          it * 64 + ((kb * 32 + hi * 16) ^ swzV));
    const char* kt = kl[cur];
    f32x16 sX = {}, sY = {};
    __builtin_amdgcn_s_setprio(1);
#pragma unroll
    for (int cc = 0; cc < 4; ++cc) {
      bf16x8 kf0 = ld_frag(kt + (q31 << 8) + ((cc * 32 + hi * 16) ^ swz));
      bf16x8 kf1 = ld_frag(kt + (q31 << 8) + (((cc + 4) * 32 + hi * 16) ^ swz));
      sX = MFMA32(kf0, qf[cc], sX);
      sY = MFMA32(kf1, qf[cc + 4], sY);
    }
    __builtin_amdgcn_s_setprio(0);
    f32x16 s;
#pragma unroll
    for (int i = 0; i < 16; ++i) s[i] = sX[i] + sY[i];

    FLASH_SOFTMAX_PACK
    uint4 pfA4, pfB4;
    EXCHANGE_SHFL

    bf16x8 pfA = __builtin_bit_cast(bf16x8, pfA4);
    bf16x8 pfB = __builtin_bit_cast(bf16x8, pfB4);
    __builtin_amdgcn_s_setprio(1);
#pragma unroll
    for (int cht = 0; cht < 4; ++cht) {
      acc[cht] = MFMA32(__builtin_bit_cast(bf16x8, vr[cht * 2 + 0]), pfA, acc[cht]);
      acc[cht] = MFMA32(__builtin_bit_cast(bf16x8, vr[cht * 2 + 1]), pfB, acc[cht]);
    }
    __builtin_amdgcn_s_setprio(0);
    __syncthreads();
  }
  FLASH_EPILOGUE
}

// ---------------- V3: R8 + permlane32_swap exchange ------------------------
template <int SPLIT>
__global__ __launch_bounds__(256, 3) void k_flash3(const __bf16* __restrict__ Qt,
                                                   const __bf16* __restrict__ Kt,
                                                   const __bf16* __restrict__ Vm,
                                                   __bf16* __restrict__ Op,
                                                   float2* __restrict__ Ml) {
  FLASH_IDS
  __shared__ __align__(16) char kl[2][8192];
  __shared__ __align__(16) char vl[2][8192];
  auto STAGE = [&](int bi, int tt) {
#pragma unroll
    for (int i = 0; i < 2; ++i) {
      int u = i * 256 + t;
      load_lds16(kbase + tt * 8192 + u * 16, &kl[bi][u * 16]);
    }
#pragma unroll
    for (int i = 0; i < 2; ++i) {
      int u = i * 256 + t, ch = u >> 2, ko = u & 3;
      load_lds16(vbase + (size_t)ch * 8192 + tt * 64 + ko * 16, &vl[bi][u * 16]);
    }
  };
  STAGE(0, 0);
  const int nit = NK / 32;
  for (int it = 0; it < nit; ++it) {
    const int cur = it & 1;
    asm volatile("s_barrier" ::: "memory");
    if (it + 1 < nit) {
      STAGE(cur ^ 1, it + 1);
      asm volatile("s_waitcnt vmcnt(4)" ::: "memory");
    } else {
      asm volatile("s_waitcnt vmcnt(0)" ::: "memory");
    }
    __builtin_amdgcn_sched_barrier(0);
    asm volatile("s_barrier" ::: "memory");

    const char* kt = kl[cur];
    f32x16 sX = {}, sY = {};
    __builtin_amdgcn_s_setprio(1);
#pragma unroll
    for (int cc = 0; cc < 4; ++cc) {
      bf16x8 kf0 = ld_frag(kt + (q31 << 8) + ((cc * 32 + hi * 16) ^ swz));
      bf16x8 kf1 = ld_frag(kt + (q31 << 8) + (((cc + 4) * 32 + hi * 16) ^ swz));
      sX = MFMA32(kf0, qf[cc], sX);
      sY = MFMA32(kf1, qf[cc + 4], sY);
    }
    __builtin_amdgcn_s_setprio(0);
    f32x16 s;
#pragma unroll
    for (int i = 0; i < 16; ++i) s[i] = sX[i] + sY[i];

    FLASH_SOFTMAX_PACK
    uint4 pfA4, pfB4;
    EXCHANGE_PL32

    const char* vt = vl[cur];
    bf16x8 pfA = __builtin_bit_cast(bf16x8, pfA4);
    bf16x8 pfB = __builtin_bit_cast(bf16x8, pfB4);
    __builtin_amdgcn_s_setprio(1);
#pragma unroll
    for (int cht = 0; cht < 4; ++cht) {
      bf16x8 vf0 = ld_frag(vt + (cht * 32 + q31) * 64 + ((hi * 16) ^ swzV));
      bf16x8 vf1 = ld_frag(vt + (cht * 32 + q31) * 64 + ((32 + hi * 16) ^ swzV));
      acc[cht] = MFMA32(vf0, pfA, acc[cht]);
      acc[cht] = MFMA32(vf1, pfB, acc[cht]);
    }
    __builtin_amdgcn_s_setprio(0);
  }
  FLASH_EPILOGUE
}

// ---------------- V23: V-from-global + permlane ----------------------------
template <int SPLIT>
__global__ __launch_bounds__(256, 2) void k_flash23(const __bf16* __restrict__ Qt,
                                                    const __bf16* __restrict__ Kt,
                                                    const __bf16* __restrict__ Vm,
                                                    __bf16* __restrict__ Op,
                                                    float2* __restrict__ Ml) {
  FLASH_IDS
  __shared__ __align__(16) char kl[2][8192];
  auto STAGE_K = [&](int bi, int tt) {
#pragma unroll
    for (int i = 0; i < 2; ++i) {
      int u = i * 256 + t;
      load_lds16(kbase + tt * 8192 + u * 16, &kl[bi][u * 16]);
    }
  };
  STAGE_K(0, 0);
  __syncthreads();
  const int nit = NK / 32;
  for (int it = 0; it < nit; ++it) {
    const int cur = it & 1;
    if (it + 1 < nit) STAGE_K(cur ^ 1, it + 1);
    int4 vr[8];
#pragma unroll
    for (int cht = 0; cht < 4; ++cht)
#pragma unroll
      for (int kb = 0; kb < 2; ++kb)
        vr[cht * 2 + kb] = *(const int4*)(vbase + (size_t)(cht * 32 + q31) * 8192 +
                                          it * 64 + ((kb * 32 + hi * 16) ^ swzV));
    const char* kt = kl[cur];
    f32x16 sX = {}, sY = {};
    __builtin_amdgcn_s_setprio(1);
#pragma unroll
    for (int cc = 0; cc < 4; ++cc) {
      bf16x8 kf0 = ld_frag(kt + (q31 << 8) + ((cc * 32 + hi * 16) ^ swz));
      bf16x8 kf1 = ld_frag(kt + (q31 << 8) + (((cc + 4) * 32 + hi * 16) ^ swz));
      sX = MFMA32(kf0, qf[cc], sX);
      sY = MFMA32(kf1, qf[cc + 4], sY);
    }
    __builtin_amdgcn_s_setprio(0);
    f32x16 s;
#pragma unroll
    for (int i = 0; i < 16; ++i) s[i] = sX[i] + sY[i];

    FLASH_SOFTMAX_PACK
    uint4 pfA4, pfB4;
    EXCHANGE_PL32

    bf16x8 pfA = __builtin_bit_cast(bf16x8, pfA4);
    bf16x8 pfB = __builtin_bit_cast(bf16x8, pfB4);
    __builtin_amdgcn_s_setprio(1);
#pragma unroll
    for (int cht = 0; cht < 4; ++cht) {
      acc[cht] = MFMA32(__builtin_bit_cast(bf16x8, vr[cht * 2 + 0]), pfA, acc[cht]);
      acc[cht] = MFMA32(__builtin_bit_cast(bf16x8, vr[cht * 2 + 1]), pfB, acc[cht]);
    }
    __builtin_amdgcn_s_setprio(0);
    __syncthreads();
  }
  FLASH_EPILOGUE
}

// ---------------- K4: combine splits + out projection + residual -----------
template <int SPLIT>
__global__ __launch_bounds__(256) void k_oproj(const __bf16* __restrict__ Op,
                                               const float2* __restrict__ Ml,
                                               const __bf16* __restrict__ wob,
                                               const float* __restrict__ bo,
                                               const float* __restrict__ xq,
                                               float* __restrict__ out) {
  const int b = blockIdx.x >> 6;
  const int n0 = (blockIdx.x & 63) << 6;
  const int t = threadIdx.x, w = t >> 6, l = t & 63, r = l & 15, g = l >> 4;
  const int nl = n0 + (w << 4) + r;

  float den = 0.f;
#pragma unroll
  for (int s = 0; s < SPLIT; ++s) den += Ml[(size_t)(s * 4 + b) * NSP + nl].y;
  float inv = 1.f / den;

  bf16x8 bfr[4];
#pragma unroll
  for (int cc = 0; cc < 4; ++cc) {
    float a8[8];
#pragma unroll
    for (int j = 0; j < 8; ++j) a8[j] = 0.f;
#pragma unroll
    for (int s = 0; s < SPLIT; ++s) {
      bf16x8 a = ld_frag(Op + ((size_t)(s * 4 + b) * NSP + nl) * 128 + cc * 32 + g * 8);
#pragma unroll
      for (int j = 0; j < 8; ++j) a8[j] += (float)a[j];
    }
#pragma unroll
    for (int j = 0; j < 8; ++j) bfr[cc][j] = (__bf16)(a8[j] * inv);
  }

  f32x4 acc[8];
#pragma unroll
  for (int oc = 0; oc < 8; ++oc)
#pragma unroll
    for (int rr = 0; rr < 4; ++rr) acc[oc][rr] = bo[oc * 16 + g * 4 + rr];
#pragma unroll
  for (int oc = 0; oc < 8; ++oc) {
#pragma unroll
    for (int cc = 0; cc < 4; ++cc) {
      bf16x8 a = ld_frag(wob + (oc * 16 + r) * 128 + cc * 32 + g * 8);
      acc[oc] = MFMA16(a, bfr[cc], acc[oc]);
    }
  }
#pragma unroll
  for (int oc = 0; oc < 8; ++oc) {
#pragma unroll
    for (int rr = 0; rr < 4; ++rr) {
      int o = oc * 16 + g * 4 + rr;
      size_t idx = ((size_t)(b * 128 + o) << 12) + nl;
      out[idx] = acc[oc][rr] + xq[idx];
    }
  }
}

extern "C" void kernel_launch(void* const* d_in, const int* in_sizes, int n_in,
                              void* d_out, int out_size, void* d_ws, size_t ws_size,
                              hipStream_t stream) {
  const float* xq = (const float*)d_in[0];
  const float* xkv = (const float*)d_in[1];
  const float* Wq = (const float*)d_in[2];
  const float* bq = (const float*)d_in[3];
  const float* Wk = (const float*)d_in[4];
  const float* bk = (const float*)d_in[5];
  const float* Wv = (const float*)d_in[6];
  const float* bv = (const float*)d_in[7];
  const float* Wo = (const float*)d_in[8];
  const float* bo = (const float*)d_in[9];
  float* out = (float*)d_out;

  char* ws = (char*)d_ws;
  __bf16* wqb = (__bf16*)(ws);
  __bf16* wkb = (__bf16*)(ws + 32768);
  __bf16* wvb = (__bf16*)(ws + 98304);
  __bf16* wob = (__bf16*)(ws + 163840);
  float* bqs = (float*)(ws + 196608);
  __bf16* Qt = (__bf16*)(ws + 197120);
  __bf16* Kt = (__bf16*)(ws + 197120 + 4194304);
  __bf16* Vm = (__bf16*)(ws + 197120 + 2 * 4194304);
  __bf16* Op = (__bf16*)(ws + 197120 + 3 * 4194304);
  float2* Ml = (float2*)(ws + 197120 + 3 * 4194304 + 33554432);

  k_prep<<<dim3(384), dim3(256), 0, stream>>>(Wq, bq, Wk, Wv, Wo, wqb, wkb, wvb, wob, bqs);
  k_proj<<<dim3(512), dim3(256), 0, stream>>>(xq, xkv, wqb, wkb, wvb, bqs, bk, bv,
                                              Qt, Kt, Vm);

  const size_t base = 197120ull + 3ull * 4194304;
  const size_t need8 = base + 33554432ull + 1048576ull;
  const size_t need4 = base + 16777216ull + 524288ull;
  if (ws_size >= need8) {
    // ABLATION: all variants do full work into the same buffers; serialized on
    // the stream; k_flash0 (known-good R8) runs LAST -> authoritative output.
    k_flash2<8><<<dim3(1024), dim3(256), 0, stream>>>(Qt, Kt, Vm, Op, Ml);
    k_flash3<8><<<dim3(1024), dim3(256), 0, stream>>>(Qt, Kt, Vm, Op, Ml);
    k_flash23<8><<<dim3(1024), dim3(256), 0, stream>>>(Qt, Kt, Vm, Op, Ml);
    k_flash0<8><<<dim3(1024), dim3(256), 0, stream>>>(Qt, Kt, Vm, Op, Ml);
    k_oproj<8><<<dim3(256), dim3(256), 0, stream>>>(Op, Ml, wob, bo, xq, out);
  } else if (ws_size >= need4) {
    float2* Ml4 = (float2*)(ws + base + 16777216);
    k_flash0<4><<<dim3(512), dim3(256), 0, stream>>>(Qt, Kt, Vm, Op, Ml4);
    k_oproj<4><<<dim3(256), dim3(256), 0, stream>>>(Op, Ml4, wob, bo, xq, out);
  } else {
    float2* Ml2 = (float2*)(ws + base + 8388608);
    k_flash0<2><<<dim3(256), dim3(256), 0, stream>>>(Qt, Kt, Vm, Op, Ml2);
    k_oproj<2><<<dim3(256), dim3(256), 0, stream>>>(Op, Ml2, wob, bo, xq, out);
  }
}

// Round 11
// 98.175 us; speedup vs baseline: 2.8608x; 2.8608x over previous
//
#include <hip/hip_runtime.h>
#include <hip/hip_bf16.h>

typedef __bf16 bf16x8 __attribute__((ext_vector_type(8)));
typedef float f32x4 __attribute__((ext_vector_type(4)));
typedef float f32x16 __attribute__((ext_vector_type(16)));
typedef unsigned u32x2 __attribute__((ext_vector_type(2)));

#define MFMA16(a, b, c) __builtin_amdgcn_mfma_f32_16x16x32_bf16(a, b, c, 0, 0, 0)
#define MFMA32(a, b, c) __builtin_amdgcn_mfma_f32_32x32x16_bf16(a, b, c, 0, 0, 0)

#if defined(__has_builtin)
#if __has_builtin(__builtin_amdgcn_permlane32_swap)
#define HAVE_PL32 1
#endif
#endif

static constexpr int NSP = 4096;   // H*W
static constexpr float SCALE_L2E = 0.25f * 1.4426950408889634f;  // SCALE * log2(e)

__device__ __forceinline__ bf16x8 ld_frag(const void* p) {
  int4 v = *(const int4*)p;
  return __builtin_bit_cast(bf16x8, v);
}

__device__ __forceinline__ unsigned pk2(float a, float b) {
  unsigned short x = __builtin_bit_cast(unsigned short, (__bf16)a);
  unsigned short y = __builtin_bit_cast(unsigned short, (__bf16)b);
  return (unsigned)x | ((unsigned)y << 16);
}

__device__ __forceinline__ void load_lds16(const void* g, void* l) {
  __builtin_amdgcn_global_load_lds(
      (const __attribute__((address_space(1))) unsigned*)g,
      (__attribute__((address_space(3))) unsigned*)l, 16, 0, 0);
}

// ---------------- K0: weight prep ------------------------------------------
__global__ void k_prep(const float* __restrict__ Wq, const float* __restrict__ bq,
                       const float* __restrict__ Wk, const float* __restrict__ Wv,
                       const float* __restrict__ Wo,
                       __bf16* __restrict__ wqb, __bf16* __restrict__ wkb,
                       __bf16* __restrict__ wvb, __bf16* __restrict__ wob,
                       float* __restrict__ bqs) {
  int i = blockIdx.x * 256 + threadIdx.x;
  if (i < 16384)      wqb[i]          = (__bf16)(Wq[i] * SCALE_L2E);
  else if (i < 49152) wkb[i - 16384]  = (__bf16)Wk[i - 16384];
  else if (i < 81920) wvb[i - 49152]  = (__bf16)Wv[i - 49152];
  else if (i < 98304) wob[i - 81920]  = (__bf16)Wo[i - 81920];
  if (i < 128) bqs[i] = bq[i] * SCALE_L2E;
}

// Per-wave transposed tile store (4-bit XOR swizzle) ------------------------
template <bool SWZ>
__device__ __forceinline__ void store_tile_T(char* myt, const f32x4* acc, int g, int r,
                                             __bf16* dst_base) {
#pragma unroll
  for (int oc = 0; oc < 8; ++oc) {
#pragma unroll
    for (int rr = 0; rr < 4; ++rr) {
      int o = oc * 16 + g * 4 + rr;
      int byte = (r << 8) + (((o << 1)) ^ (r << 4));
      *(__bf16*)(myt + byte) = (__bf16)acc[oc][rr];
    }
  }
  int l = g * 16 + r;
#pragma unroll
  for (int p = 0; p < 4; ++p) {
    int u = p * 64 + l, row = u >> 4, seg = u & 15;
    int byte = (row << 8) + (seg << 4);
    if (!SWZ) byte ^= (row & 15) << 4;
    int4 v = *(int4*)(myt + byte);
    *(int4*)(dst_base + row * 128 + seg * 8) = v;
  }
}

// ---------------- K1: fused Q / K+V projections ----------------------------
__global__ __launch_bounds__(256) void k_proj(const float* __restrict__ xq,
                                              const float* __restrict__ xkv,
                                              const __bf16* __restrict__ wqb,
                                              const __bf16* __restrict__ wkb,
                                              const __bf16* __restrict__ wvb,
                                              const float* __restrict__ bqs,
                                              const float* __restrict__ bk,
                                              const float* __restrict__ bv,
                                              __bf16* __restrict__ Qt,
                                              __bf16* __restrict__ Kt,
                                              __bf16* __restrict__ Vm) {
  const int t = threadIdx.x, w = t >> 6, l = t & 63, r = l & 15, g = l >> 4;
  __shared__ __align__(16) char lds[16384];
  char* myt = lds + (w << 12);

  if (blockIdx.x < 256) {
    const int b = blockIdx.x >> 6;
    const int n0 = (blockIdx.x & 63) << 6;
    const int nl = n0 + (w << 4) + r;
    const float* xb = xq + ((size_t)b << 19);
    bf16x8 bx[4];
#pragma unroll
    for (int cc = 0; cc < 4; ++cc) {
#pragma unroll
      for (int i = 0; i < 8; ++i) {
        int c = cc * 32 + g * 8 + i;
        bx[cc][i] = (__bf16)xb[c * 4096 + nl];
      }
    }
    f32x4 acc[8];
#pragma unroll
    for (int oc = 0; oc < 8; ++oc)
#pragma unroll
      for (int rr = 0; rr < 4; ++rr) acc[oc][rr] = bqs[oc * 16 + g * 4 + rr];
#pragma unroll
    for (int oc = 0; oc < 8; ++oc) {
#pragma unroll
      for (int cc = 0; cc < 4; ++cc) {
        bf16x8 a = ld_frag(wqb + (oc * 16 + r) * 128 + cc * 32 + g * 8);
        acc[oc] = MFMA16(a, bx[cc], acc[oc]);
      }
    }
    store_tile_T<false>(myt, acc, g, r, Qt + ((size_t)(b * NSP + n0 + w * 16)) * 128);
  } else {
    const int bid = blockIdx.x - 256;
    const int b = bid >> 6;
    const int n0 = (bid & 63) << 6;
    const int nl = n0 + (w << 4) + r;
    const float* xb = xkv + ((size_t)b << 20);
    bf16x8 bx[8];
#pragma unroll
    for (int cc = 0; cc < 8; ++cc) {
#pragma unroll
      for (int i = 0; i < 8; ++i) {
        int c = cc * 32 + g * 8 + i;
        bx[cc][i] = (__bf16)xb[(size_t)c * 4096 + nl];
      }
    }
    f32x4 acc[8];
#pragma unroll
    for (int oc = 0; oc < 8; ++oc)
#pragma unroll
      for (int rr = 0; rr < 4; ++rr) acc[oc][rr] = bk[oc * 16 + g * 4 + rr];
#pragma unroll
    for (int oc = 0; oc < 8; ++oc) {
#pragma unroll
      for (int cc = 0; cc < 8; ++cc) {
        bf16x8 a = ld_frag(wkb + (oc * 16 + r) * 256 + cc * 32 + g * 8);
        acc[oc] = MFMA16(a, bx[cc], acc[oc]);
      }
    }
    store_tile_T<true>(myt, acc, g, r, Kt + ((size_t)(b * NSP + n0 + w * 16)) * 128);

    f32x4 av[8];
#pragma unroll
    for (int oc = 0; oc < 8; ++oc)
#pragma unroll
      for (int rr = 0; rr < 4; ++rr) av[oc][rr] = bv[oc * 16 + g * 4 + rr];
#pragma unroll
    for (int oc = 0; oc < 8; ++oc) {
#pragma unroll
      for (int cc = 0; cc < 8; ++cc) {
        bf16x8 a = ld_frag(wvb + (oc * 16 + r) * 256 + cc * 32 + g * 8);
        av[oc] = MFMA16(a, bx[cc], av[oc]);
      }
    }
    // V [B][128][N], granule-swizzled: key n at n ^ (((ch>>1)&3)<<3)
#pragma unroll
    for (int oc = 0; oc < 8; ++oc) {
#pragma unroll
      for (int rr = 0; rr < 4; ++rr) {
        int o = oc * 16 + g * 4 + rr;
        Vm[((size_t)(b * 128 + o) << 12) + (nl ^ (((o >> 1) & 3) << 3))] = (__bf16)av[oc][rr];
      }
    }
  }
}

// ---------------- K3: flash attention (R8 skeleton + permlane exchange) ----
// 4 waves x 32 q = 128 q/block; grid = 32 qtiles * 4 b * SPLIT.
// Counted-vmcnt barriers; K 4-bit swizzle; V granule swizzle; P exchanged
// across lane-halves via v_permlane32_swap (no ds_bpermute on the chain).
template <int SPLIT>
__global__ __launch_bounds__(256, 3) void k_flash(const __bf16* __restrict__ Qt,
                                                  const __bf16* __restrict__ Kt,
                                                  const __bf16* __restrict__ Vm,
                                                  __bf16* __restrict__ Op,
                                                  float2* __restrict__ Ml) {
  const int bid = blockIdx.x;
  const int combo = bid & (4 * SPLIT - 1), qtile = bid / (4 * SPLIT);
  const int b = combo & 3, ks = combo >> 2;
  const int q0 = qtile << 7;
  const int NK = NSP / SPLIT;
  const int t = threadIdx.x, w = t >> 6, l = t & 63;
  const int q31 = l & 31, hi = l >> 5;
  const int swz = (q31 & 15) << 4;
  const int swzV = ((q31 >> 1) & 3) << 4;

  __shared__ __align__(16) char kl[2][8192];
  __shared__ __align__(16) char vl[2][8192];

  const int qA = q0 + w * 32 + q31;
  const __bf16* qp = Qt + ((size_t)(b * NSP + qA)) * 128;
  bf16x8 qf[8];
#pragma unroll
  for (int cc = 0; cc < 8; ++cc) qf[cc] = ld_frag(qp + cc * 16 + hi * 8);

  f32x16 acc[4];
#pragma unroll
  for (int c = 0; c < 4; ++c)
#pragma unroll
    for (int i = 0; i < 16; ++i) acc[c][i] = 0.f;
  f32x4 lp = (f32x4){0.f, 0.f, 0.f, 0.f};

  const char* kbase = (const char*)(Kt + ((size_t)(b * NSP) + ks * NK) * 128);
  const char* vbase = (const char*)(Vm + (size_t)b * 128 * NSP + ks * NK);

  auto STAGE = [&](int bi, int tt) {
#pragma unroll
    for (int i = 0; i < 2; ++i) {  // K: 8 KB, 32 key-rows x 256 B (pre-swizzled)
      int u = i * 256 + t;
      load_lds16(kbase + tt * 8192 + u * 16, &kl[bi][u * 16]);
    }
#pragma unroll
    for (int i = 0; i < 2; ++i) {  // V: 8 KB, 128 ch-rows x 64 B (pre-swizzled)
      int u = i * 256 + t, ch = u >> 2, ko = u & 3;
      load_lds16(vbase + (size_t)ch * 8192 + tt * 64 + ko * 16, &vl[bi][u * 16]);
    }
  };

  STAGE(0, 0);

  const int nit = NK / 32;
  for (int it = 0; it < nit; ++it) {
    const int cur = it & 1;
    // barrier A: all waves done reading buf[cur^1] -> safe to overwrite
    asm volatile("s_barrier" ::: "memory");
    if (it + 1 < nit) {
      STAGE(cur ^ 1, it + 1);
      asm volatile("s_waitcnt vmcnt(4)" ::: "memory");   // my tile-it loads done
    } else {
      asm volatile("s_waitcnt vmcnt(0)" ::: "memory");
    }
    __builtin_amdgcn_sched_barrier(0);
    // barrier B: every wave's tile-it loads complete
    asm volatile("s_barrier" ::: "memory");

    // ---- QK^T: two independent accumulator chains ----
    const char* kt = kl[cur];
    f32x16 sX = {}, sY = {};
    __builtin_amdgcn_s_setprio(1);
#pragma unroll
    for (int cc = 0; cc < 4; ++cc) {
      bf16x8 kf0 = ld_frag(kt + (q31 << 8) + ((cc * 32 + hi * 16) ^ swz));
      bf16x8 kf1 = ld_frag(kt + (q31 << 8) + (((cc + 4) * 32 + hi * 16) ^ swz));
      sX = MFMA32(kf0, qf[cc], sX);
      sY = MFMA32(kf1, qf[cc + 4], sY);
    }
    __builtin_amdgcn_s_setprio(0);
    f32x16 s;
#pragma unroll
    for (int i = 0; i < 16; ++i) s[i] = sX[i] + sY[i];

    // ---- P = exp2(S); l in 4 independent chains ----
#pragma unroll
    for (int i = 0; i < 16; ++i) s[i] = exp2f(s[i]);
#pragma unroll
    for (int i = 0; i < 16; ++i) lp[i & 3] += s[i];

    // ---- pack to bf16 + cross-half exchange (permlane32_swap) ----
    unsigned pA[4][2];
#pragma unroll
    for (int q4 = 0; q4 < 4; ++q4) {
      pA[q4][0] = pk2(s[4 * q4 + 0], s[4 * q4 + 1]);
      pA[q4][1] = pk2(s[4 * q4 + 2], s[4 * q4 + 3]);
    }
    uint4 pfA4, pfB4;
#ifdef HAVE_PL32
    {
      u32x2 r_;
      r_ = __builtin_amdgcn_permlane32_swap(pA[0][0], pA[1][0], false, false);
      pfA4.x = r_[0]; pfA4.z = r_[1];
      r_ = __builtin_amdgcn_permlane32_swap(pA[0][1], pA[1][1], false, false);
      pfA4.y = r_[0]; pfA4.w = r_[1];
      r_ = __builtin_amdgcn_permlane32_swap(pA[2][0], pA[3][0], false, false);
      pfB4.x = r_[0]; pfB4.z = r_[1];
      r_ = __builtin_amdgcn_permlane32_swap(pA[2][1], pA[3][1], false, false);
      pfB4.y = r_[0]; pfB4.w = r_[1];
    }
#else
    {
      unsigned rA[4][2];
#pragma unroll
      for (int q4 = 0; q4 < 4; ++q4) {
        rA[q4][0] = __shfl_xor(pA[q4][0], 32);
        rA[q4][1] = __shfl_xor(pA[q4][1], 32);
      }
      pfA4.x = hi ? rA[1][0] : pA[0][0];
      pfA4.y = hi ? rA[1][1] : pA[0][1];
      pfA4.z = hi ? pA[1][0] : rA[0][0];
      pfA4.w = hi ? pA[1][1] : rA[0][1];
      pfB4.x = hi ? rA[3][0] : pA[2][0];
      pfB4.y = hi ? rA[3][1] : pA[2][1];
      pfB4.z = hi ? pA[3][0] : rA[2][0];
      pfB4.w = hi ? pA[3][1] : rA[2][1];
    }
#endif

    // ---- PV ----
    const char* vt = vl[cur];
    bf16x8 pfA = __builtin_bit_cast(bf16x8, pfA4);
    bf16x8 pfB = __builtin_bit_cast(bf16x8, pfB4);
    __builtin_amdgcn_s_setprio(1);
#pragma unroll
    for (int cht = 0; cht < 4; ++cht) {
      bf16x8 vf0 = ld_frag(vt + (cht * 32 + q31) * 64 + ((hi * 16) ^ swzV));
      bf16x8 vf1 = ld_frag(vt + (cht * 32 + q31) * 64 + ((32 + hi * 16) ^ swzV));
      acc[cht] = MFMA32(vf0, pfA, acc[cht]);
      acc[cht] = MFMA32(vf1, pfB, acc[cht]);
    }
    __builtin_amdgcn_s_setprio(0);
  }

  // ---- l reduce + partial store (UNNORMALIZED O) ----
  float lsum = (lp[0] + lp[1]) + (lp[2] + lp[3]);
  lsum += __shfl_xor(lsum, 32);

  const size_t rowA = (size_t)((ks * 4 + b) * NSP + qA) * 128;
#pragma unroll
  for (int cht = 0; cht < 4; ++cht) {
#pragma unroll
    for (int qq = 0; qq < 4; ++qq) {
      uint2 va;
      va.x = pk2(acc[cht][4 * qq + 0], acc[cht][4 * qq + 1]);
      va.y = pk2(acc[cht][4 * qq + 2], acc[cht][4 * qq + 3]);
      *(uint2*)(Op + rowA + cht * 32 + qq * 8 + hi * 4) = va;
    }
  }
  if (hi == 0) {
    Ml[(size_t)(ks * 4 + b) * NSP + qA] = make_float2(0.f, lsum);
  }
}

// ---------------- K4: combine splits + out projection + residual -----------
template <int SPLIT>
__global__ __launch_bounds__(256) void k_oproj(const __bf16* __restrict__ Op,
                                               const float2* __restrict__ Ml,
                                               const __bf16* __restrict__ wob,
                                               const float* __restrict__ bo,
                                               const float* __restrict__ xq,
                                               float* __restrict__ out) {
  const int b = blockIdx.x >> 6;
  const int n0 = (blockIdx.x & 63) << 6;
  const int t = threadIdx.x, w = t >> 6, l = t & 63, r = l & 15, g = l >> 4;
  const int nl = n0 + (w << 4) + r;

  float den = 0.f;
#pragma unroll
  for (int s = 0; s < SPLIT; ++s) den += Ml[(size_t)(s * 4 + b) * NSP + nl].y;
  float inv = 1.f / den;

  bf16x8 bfr[4];
#pragma unroll
  for (int cc = 0; cc < 4; ++cc) {
    float a8[8];
#pragma unroll
    for (int j = 0; j < 8; ++j) a8[j] = 0.f;
#pragma unroll
    for (int s = 0; s < SPLIT; ++s) {
      bf16x8 a = ld_frag(Op + ((size_t)(s * 4 + b) * NSP + nl) * 128 + cc * 32 + g * 8);
#pragma unroll
      for (int j = 0; j < 8; ++j) a8[j] += (float)a[j];
    }
#pragma unroll
    for (int j = 0; j < 8; ++j) bfr[cc][j] = (__bf16)(a8[j] * inv);
  }

  f32x4 acc[8];
#pragma unroll
  for (int oc = 0; oc < 8; ++oc)
#pragma unroll
    for (int rr = 0; rr < 4; ++rr) acc[oc][rr] = bo[oc * 16 + g * 4 + rr];
#pragma unroll
  for (int oc = 0; oc < 8; ++oc) {
#pragma unroll
    for (int cc = 0; cc < 4; ++cc) {
      bf16x8 a = ld_frag(wob + (oc * 16 + r) * 128 + cc * 32 + g * 8);
      acc[oc] = MFMA16(a, bfr[cc], acc[oc]);
    }
  }
#pragma unroll
  for (int oc = 0; oc < 8; ++oc) {
#pragma unroll
    for (int rr = 0; rr < 4; ++rr) {
      int o = oc * 16 + g * 4 + rr;
      size_t idx = ((size_t)(b * 128 + o) << 12) + nl;
      out[idx] = acc[oc][rr] + xq[idx];
    }
  }
}

extern "C" void kernel_launch(void* const* d_in, const int* in_sizes, int n_in,
                              void* d_out, int out_size, void* d_ws, size_t ws_size,
                              hipStream_t stream) {
  const float* xq = (const float*)d_in[0];
  const float* xkv = (const float*)d_in[1];
  const float* Wq = (const float*)d_in[2];
  const float* bq = (const float*)d_in[3];
  const float* Wk = (const float*)d_in[4];
  const float* bk = (const float*)d_in[5];
  const float* Wv = (const float*)d_in[6];
  const float* bv = (const float*)d_in[7];
  const float* Wo = (const float*)d_in[8];
  const float* bo = (const float*)d_in[9];
  float* out = (float*)d_out;

  char* ws = (char*)d_ws;
  __bf16* wqb = (__bf16*)(ws);
  __bf16* wkb = (__bf16*)(ws + 32768);
  __bf16* wvb = (__bf16*)(ws + 98304);
  __bf16* wob = (__bf16*)(ws + 163840);
  float* bqs = (float*)(ws + 196608);
  __bf16* Qt = (__bf16*)(ws + 197120);
  __bf16* Kt = (__bf16*)(ws + 197120 + 4194304);
  __bf16* Vm = (__bf16*)(ws + 197120 + 2 * 4194304);
  __bf16* Op = (__bf16*)(ws + 197120 + 3 * 4194304);
  float2* Ml = (float2*)(ws + 197120 + 3 * 4194304 + 33554432);

  k_prep<<<dim3(384), dim3(256), 0, stream>>>(Wq, bq, Wk, Wv, Wo, wqb, wkb, wvb, wob, bqs);
  k_proj<<<dim3(512), dim3(256), 0, stream>>>(xq, xkv, wqb, wkb, wvb, bqs, bk, bv,
                                              Qt, Kt, Vm);

  const size_t base = 197120ull + 3ull * 4194304;
  const size_t need8 = base + 33554432ull + 1048576ull;
  const size_t need4 = base + 16777216ull + 524288ull;
  if (ws_size >= need8) {
    k_flash<8><<<dim3(1024), dim3(256), 0, stream>>>(Qt, Kt, Vm, Op, Ml);
    k_oproj<8><<<dim3(256), dim3(256), 0, stream>>>(Op, Ml, wob, bo, xq, out);
  } else if (ws_size >= need4) {
    float2* Ml4 = (float2*)(ws + base + 16777216);
    k_flash<4><<<dim3(512), dim3(256), 0, stream>>>(Qt, Kt, Vm, Op, Ml4);
    k_oproj<4><<<dim3(256), dim3(256), 0, stream>>>(Op, Ml4, wob, bo, xq, out);
  } else {
    float2* Ml2 = (float2*)(ws + base + 8388608);
    k_flash<2><<<dim3(256), dim3(256), 0, stream>>>(Qt, Kt, Vm, Op, Ml2);
    k_oproj<2><<<dim3(256), dim3(256), 0, stream>>>(Op, Ml2, wob, bo, xq, out);
  }
}